// Round 6
// baseline (160.947 us; speedup 1.0000x reference)
//
#include <hip/hip_runtime.h>

#define SEQ_L 512
#define DIM 256

typedef float f4 __attribute__((ext_vector_type(4)));

// ---------------------------------------------------------------------------
// Kernel A: out_row = l2norm(X_row @ W + b) for q/k/v, selected by blockIdx.y.
// 8 rows/block, 256 threads (thread t owns output column t).
// ---------------------------------------------------------------------------
__global__ __launch_bounds__(256) void proj_norm3_kernel(
    const float* __restrict__ Xq, const float* __restrict__ Wq,
    const float* __restrict__ bq, float* __restrict__ oq,
    const float* __restrict__ Xk, const float* __restrict__ Wk,
    const float* __restrict__ bk, float* __restrict__ ok,
    const float* __restrict__ Xv, const float* __restrict__ Wv,
    const float* __restrict__ bv, float* __restrict__ ov)
{
    const float* X; const float* W; const float* bias; float* out;
    if (blockIdx.y == 0)      { X = Xq; W = Wq; bias = bq; out = oq; }
    else if (blockIdx.y == 1) { X = Xk; W = Wk; bias = bk; out = ok; }
    else                      { X = Xv; W = Wv; bias = bv; out = ov; }

    const int ROWS = 8;
    __shared__ __align__(16) float xs[ROWS][DIM];
    __shared__ float red[ROWS][4];

    const int t  = threadIdx.x;
    const int r0 = blockIdx.x * ROWS;

    #pragma unroll
    for (int r = 0; r < ROWS; ++r)
        xs[r][t] = X[(size_t)(r0 + r) * DIM + t];
    __syncthreads();

    const float b = bias[t];
    float acc[ROWS];
    #pragma unroll
    for (int r = 0; r < ROWS; ++r) acc[r] = b;

    #pragma unroll 2
    for (int d4 = 0; d4 < DIM / 4; ++d4) {
        const float w0 = W[(size_t)(d4 * 4 + 0) * DIM + t];
        const float w1 = W[(size_t)(d4 * 4 + 1) * DIM + t];
        const float w2 = W[(size_t)(d4 * 4 + 2) * DIM + t];
        const float w3 = W[(size_t)(d4 * 4 + 3) * DIM + t];
        #pragma unroll
        for (int r = 0; r < ROWS; ++r) {
            const f4 xv = ((const f4*)xs[r])[d4];   // LDS broadcast, b128
            acc[r] += xv.x * w0 + xv.y * w1 + xv.z * w2 + xv.w * w3;
        }
    }

    const int lane = t & 63;
    const int wid  = t >> 6;

    #pragma unroll
    for (int r = 0; r < ROWS; ++r) {
        float ss = acc[r] * acc[r];
        #pragma unroll
        for (int off = 32; off >= 1; off >>= 1)
            ss += __shfl_down(ss, off, 64);
        if (lane == 0) red[r][wid] = ss;
    }
    __syncthreads();

    #pragma unroll
    for (int r = 0; r < ROWS; ++r) {
        const float s = red[r][0] + red[r][1] + red[r][2] + red[r][3];
        const float scale = rsqrtf(fmaxf(s, 1e-12f));
        out[(size_t)(r0 + r) * DIM + t] = acc[r] * scale;
    }
}

// ---------------------------------------------------------------------------
// Kernel B: out[b,l,m] = 0.025 * dot(q[b,l], k[b,m])   (qk term, L2-resident k)
// 4 l-rows per block -> k traffic amortized 4x.
// ---------------------------------------------------------------------------
__global__ __launch_bounds__(256) void qk4_kernel(
    const float* __restrict__ q, const float* __restrict__ k,
    float* __restrict__ out)
{
    const int l0    = blockIdx.x * 4;
    const int b     = l0 >> 9;
    const int lane  = threadIdx.x & 63;
    const int wave  = threadIdx.x >> 6;
    const int m_sub = lane & 7;
    const int d_sub = lane >> 3;

    f4 qf[4][8];
    #pragma unroll
    for (int r = 0; r < 4; ++r) {
        const f4* q4 = (const f4*)(q + (size_t)(l0 + r) * DIM);
        #pragma unroll
        for (int c = 0; c < 8; ++c) qf[r][c] = q4[c * 8 + d_sub];
    }

    const f4* k4 = (const f4*)(k + (size_t)b * SEQ_L * DIM);

    for (int m0 = wave * 8; m0 < SEQ_L; m0 += 32) {
        const size_t base = (size_t)(m0 + m_sub) * (DIM / 4) + d_sub;
        f4 kf[8];
        #pragma unroll
        for (int c = 0; c < 8; ++c) kf[c] = k4[base + c * 8];

        #pragma unroll
        for (int r = 0; r < 4; ++r) {
            float sa = 0.f, sb = 0.f;
            #pragma unroll
            for (int c = 0; c < 8; ++c) {
                sa += qf[r][c].x * kf[c].x + qf[r][c].y * kf[c].y;
                sb += qf[r][c].z * kf[c].z + qf[r][c].w * kf[c].w;
            }
            float s = sa + sb;
            s += __shfl_xor(s, 8, 64);
            s += __shfl_xor(s, 16, 64);
            s += __shfl_xor(s, 32, 64);
            if (lane < 8)
                out[(size_t)(l0 + r) * SEQ_L + m0 + lane] = s * 0.025f;
        }
    }
}

// ---------------------------------------------------------------------------
// Kernel C: out[b,l,m] += 0.0375 * dot(q[b,l], edge[b,l,m])   (HBM stream)
// Exact R3 structure (the 127 us best): grid (1024, 2), 2 groups per
// iteration, compiler-scheduled. SINGLE CHANGE vs R3: plain loads instead of
// __builtin_nontemporal_load -- let L2 aggregate the read stream (fill/copy
// hit 6.3-6.8 TB/s through L2; NT bypasses it).
// ---------------------------------------------------------------------------
__global__ __launch_bounds__(256) void edge_kernel(
    const float* __restrict__ q, const float* __restrict__ edge,
    float* __restrict__ out)
{
    const int bl    = blockIdx.x;
    const int lane  = threadIdx.x & 63;
    const int wave  = threadIdx.x >> 6;
    const int m_sub = lane & 7;
    const int d_sub = lane >> 3;

    const f4* q4 = (const f4*)(q + (size_t)bl * DIM);
    f4 qf[8];
    #pragma unroll
    for (int c = 0; c < 8; ++c) qf[c] = q4[c * 8 + d_sub];

    const f4* e4 = (const f4*)(edge + (size_t)bl * SEQ_L * DIM);
    float* orow = out + (size_t)bl * SEQ_L;

    const int mbase = blockIdx.y * 256;
    for (int m0 = mbase + wave * 8; m0 < mbase + 256; m0 += 64) {
        const int m1 = m0 + 32;
        const size_t ba0 = (size_t)(m0 + m_sub) * (DIM / 4) + d_sub;
        const size_t ba1 = (size_t)(m1 + m_sub) * (DIM / 4) + d_sub;

        f4 e0[8], e1[8];
        #pragma unroll
        for (int c = 0; c < 8; ++c) {
            e0[c] = e4[ba0 + c * 8];
            e1[c] = e4[ba1 + c * 8];
        }

        float base0 = 0.f, base1 = 0.f;
        if (lane < 8) { base0 = orow[m0 + lane]; base1 = orow[m1 + lane]; }

        float sa0 = 0.f, sb0 = 0.f, sa1 = 0.f, sb1 = 0.f;
        #pragma unroll
        for (int c = 0; c < 8; ++c) {
            sa0 += qf[c].x * e0[c].x + qf[c].y * e0[c].y;
            sb0 += qf[c].z * e0[c].z + qf[c].w * e0[c].w;
            sa1 += qf[c].x * e1[c].x + qf[c].y * e1[c].y;
            sb1 += qf[c].z * e1[c].z + qf[c].w * e1[c].w;
        }
        float s0 = sa0 + sb0, s1 = sa1 + sb1;
        s0 += __shfl_xor(s0, 8, 64);  s1 += __shfl_xor(s1, 8, 64);
        s0 += __shfl_xor(s0, 16, 64); s1 += __shfl_xor(s1, 16, 64);
        s0 += __shfl_xor(s0, 32, 64); s1 += __shfl_xor(s1, 32, 64);

        if (lane < 8) {
            orow[m0 + lane] = fmaf(s0, 0.0375f, base0);
            orow[m1 + lane] = fmaf(s1, 0.0375f, base1);
        }
    }
}

// ---------------------------------------------------------------------------
// Host launcher
// ---------------------------------------------------------------------------
extern "C" void kernel_launch(void* const* d_in, const int* in_sizes, int n_in,
                              void* d_out, int out_size, void* d_ws, size_t ws_size,
                              hipStream_t stream) {
    const float* queries = (const float*)d_in[0];
    const float* keys    = (const float*)d_in[1];
    const float* values  = (const float*)d_in[2];
    // d_in[3] = relative_encoding_lookup: DEAD CODE (overwritten in reference).
    const float* edge    = (const float*)d_in[4];
    const float* Wq = (const float*)d_in[5];
    const float* bq = (const float*)d_in[6];
    const float* Wk = (const float*)d_in[7];
    const float* bk = (const float*)d_in[8];
    const float* Wv = (const float*)d_in[9];
    const float* bv = (const float*)d_in[10];

    float* out = (float*)d_out;

    const int B = in_sizes[0] / (SEQ_L * DIM);           // 2
    const size_t scores_sz = (size_t)B * SEQ_L * SEQ_L;
    const size_t qkv_sz    = (size_t)B * SEQ_L * DIM;

    float* v_out = out + scores_sz;           // output slot 1: v
    float* q_out = out + scores_sz + qkv_sz;  // output slot 2: q
    float* k_ws  = (float*)d_ws;              // k -> scratch

    const int rows = B * SEQ_L;               // 1024

    dim3 pgrid(rows / 8, 3);
    proj_norm3_kernel<<<pgrid, 256, 0, stream>>>(
        queries, Wq, bq, q_out,
        keys,    Wk, bk, k_ws,
        values,  Wv, bv, v_out);

    qk4_kernel<<<rows / 4, 256, 0, stream>>>(q_out, k_ws, out);

    dim3 egrid(rows, 2);
    edge_kernel<<<egrid, 256, 0, stream>>>(q_out, edge, out);
}

// Round 7
// 126.385 us; speedup vs baseline: 1.2735x; 1.2735x over previous
//
#include <hip/hip_runtime.h>

#define SEQ_L 512
#define DIM 256

typedef float f4 __attribute__((ext_vector_type(4)));

// ---------------------------------------------------------------------------
// Kernel A: out_row = l2norm(X_row @ W + b) for q/k/v, selected by blockIdx.y.
// 4 rows/block (R7: was 8) -> half the per-thread FMA chain, 2x block TLP.
// ---------------------------------------------------------------------------
__global__ __launch_bounds__(256) void proj_norm3_kernel(
    const float* __restrict__ Xq, const float* __restrict__ Wq,
    const float* __restrict__ bq, float* __restrict__ oq,
    const float* __restrict__ Xk, const float* __restrict__ Wk,
    const float* __restrict__ bk, float* __restrict__ ok,
    const float* __restrict__ Xv, const float* __restrict__ Wv,
    const float* __restrict__ bv, float* __restrict__ ov)
{
    const float* X; const float* W; const float* bias; float* out;
    if (blockIdx.y == 0)      { X = Xq; W = Wq; bias = bq; out = oq; }
    else if (blockIdx.y == 1) { X = Xk; W = Wk; bias = bk; out = ok; }
    else                      { X = Xv; W = Wv; bias = bv; out = ov; }

    const int ROWS = 4;
    __shared__ __align__(16) float xs[ROWS][DIM];
    __shared__ float red[ROWS][4];

    const int t  = threadIdx.x;
    const int r0 = blockIdx.x * ROWS;

    #pragma unroll
    for (int r = 0; r < ROWS; ++r)
        xs[r][t] = X[(size_t)(r0 + r) * DIM + t];
    __syncthreads();

    const float b = bias[t];
    float acc[ROWS];
    #pragma unroll
    for (int r = 0; r < ROWS; ++r) acc[r] = b;

    #pragma unroll 2
    for (int d4 = 0; d4 < DIM / 4; ++d4) {
        const float w0 = W[(size_t)(d4 * 4 + 0) * DIM + t];
        const float w1 = W[(size_t)(d4 * 4 + 1) * DIM + t];
        const float w2 = W[(size_t)(d4 * 4 + 2) * DIM + t];
        const float w3 = W[(size_t)(d4 * 4 + 3) * DIM + t];
        #pragma unroll
        for (int r = 0; r < ROWS; ++r) {
            const f4 xv = ((const f4*)xs[r])[d4];   // LDS broadcast, b128
            acc[r] += xv.x * w0 + xv.y * w1 + xv.z * w2 + xv.w * w3;
        }
    }

    const int lane = t & 63;
    const int wid  = t >> 6;

    #pragma unroll
    for (int r = 0; r < ROWS; ++r) {
        float ss = acc[r] * acc[r];
        #pragma unroll
        for (int off = 32; off >= 1; off >>= 1)
            ss += __shfl_down(ss, off, 64);
        if (lane == 0) red[r][wid] = ss;
    }
    __syncthreads();

    #pragma unroll
    for (int r = 0; r < ROWS; ++r) {
        const float s = red[r][0] + red[r][1] + red[r][2] + red[r][3];
        const float scale = rsqrtf(fmaxf(s, 1e-12f));
        out[(size_t)(r0 + r) * DIM + t] = acc[r] * scale;
    }
}

// ---------------------------------------------------------------------------
// Kernel B: out[b,l,m] = 0.025 * dot(q[b,l], k[b,m])   (qk term, L2-resident k)
// 4 l-rows per block -> k traffic amortized 4x. UNCHANGED from R3 (127us best).
// ---------------------------------------------------------------------------
__global__ __launch_bounds__(256) void qk4_kernel(
    const float* __restrict__ q, const float* __restrict__ k,
    float* __restrict__ out)
{
    const int l0    = blockIdx.x * 4;
    const int b     = l0 >> 9;
    const int lane  = threadIdx.x & 63;
    const int wave  = threadIdx.x >> 6;
    const int m_sub = lane & 7;
    const int d_sub = lane >> 3;

    f4 qf[4][8];
    #pragma unroll
    for (int r = 0; r < 4; ++r) {
        const f4* q4 = (const f4*)(q + (size_t)(l0 + r) * DIM);
        #pragma unroll
        for (int c = 0; c < 8; ++c) qf[r][c] = q4[c * 8 + d_sub];
    }

    const f4* k4 = (const f4*)(k + (size_t)b * SEQ_L * DIM);

    for (int m0 = wave * 8; m0 < SEQ_L; m0 += 32) {
        const size_t base = (size_t)(m0 + m_sub) * (DIM / 4) + d_sub;
        f4 kf[8];
        #pragma unroll
        for (int c = 0; c < 8; ++c) kf[c] = k4[base + c * 8];

        #pragma unroll
        for (int r = 0; r < 4; ++r) {
            float sa = 0.f, sb = 0.f;
            #pragma unroll
            for (int c = 0; c < 8; ++c) {
                sa += qf[r][c].x * kf[c].x + qf[r][c].y * kf[c].y;
                sb += qf[r][c].z * kf[c].z + qf[r][c].w * kf[c].w;
            }
            float s = sa + sb;
            s += __shfl_xor(s, 8, 64);
            s += __shfl_xor(s, 16, 64);
            s += __shfl_xor(s, 32, 64);
            if (lane < 8)
                out[(size_t)(l0 + r) * SEQ_L + m0 + lane] = s * 0.025f;
        }
    }
}

// ---------------------------------------------------------------------------
// Kernel C: out[b,l,m] += 0.0375 * dot(q[b,l], edge[b,l,m])   (HBM stream)
// Inner loop byte-identical to R3 (127us best): NT loads (PROVEN +27% in R6
// A/B -- zero-reuse 537MB stream must bypass the 4MB/XCD L2), 2 groups per
// iteration, compiler-scheduled, RMW of out. R7 single change: y-split x4
// (grid 4096, 128KB stream/block) for finer scheduling granularity / tail.
// ---------------------------------------------------------------------------
__global__ __launch_bounds__(256) void edge_kernel(
    const float* __restrict__ q, const float* __restrict__ edge,
    float* __restrict__ out)
{
    const int bl    = blockIdx.x;
    const int lane  = threadIdx.x & 63;
    const int wave  = threadIdx.x >> 6;
    const int m_sub = lane & 7;
    const int d_sub = lane >> 3;

    const f4* q4 = (const f4*)(q + (size_t)bl * DIM);
    f4 qf[8];
    #pragma unroll
    for (int c = 0; c < 8; ++c) qf[c] = q4[c * 8 + d_sub];

    const f4* e4 = (const f4*)(edge + (size_t)bl * SEQ_L * DIM);
    float* orow = out + (size_t)bl * SEQ_L;

    const int mbase = blockIdx.y * 128;
    for (int m0 = mbase + wave * 8; m0 < mbase + 128; m0 += 64) {
        const int m1 = m0 + 32;
        const size_t ba0 = (size_t)(m0 + m_sub) * (DIM / 4) + d_sub;
        const size_t ba1 = (size_t)(m1 + m_sub) * (DIM / 4) + d_sub;

        f4 e0[8], e1[8];
        #pragma unroll
        for (int c = 0; c < 8; ++c) {
            e0[c] = __builtin_nontemporal_load(&e4[ba0 + c * 8]);
            e1[c] = __builtin_nontemporal_load(&e4[ba1 + c * 8]);
        }

        float base0 = 0.f, base1 = 0.f;
        if (lane < 8) { base0 = orow[m0 + lane]; base1 = orow[m1 + lane]; }

        float sa0 = 0.f, sb0 = 0.f, sa1 = 0.f, sb1 = 0.f;
        #pragma unroll
        for (int c = 0; c < 8; ++c) {
            sa0 += qf[c].x * e0[c].x + qf[c].y * e0[c].y;
            sb0 += qf[c].z * e0[c].z + qf[c].w * e0[c].w;
            sa1 += qf[c].x * e1[c].x + qf[c].y * e1[c].y;
            sb1 += qf[c].z * e1[c].z + qf[c].w * e1[c].w;
        }
        float s0 = sa0 + sb0, s1 = sa1 + sb1;
        s0 += __shfl_xor(s0, 8, 64);  s1 += __shfl_xor(s1, 8, 64);
        s0 += __shfl_xor(s0, 16, 64); s1 += __shfl_xor(s1, 16, 64);
        s0 += __shfl_xor(s0, 32, 64); s1 += __shfl_xor(s1, 32, 64);

        if (lane < 8) {
            orow[m0 + lane] = fmaf(s0, 0.0375f, base0);
            orow[m1 + lane] = fmaf(s1, 0.0375f, base1);
        }
    }
}

// ---------------------------------------------------------------------------
// Host launcher
// ---------------------------------------------------------------------------
extern "C" void kernel_launch(void* const* d_in, const int* in_sizes, int n_in,
                              void* d_out, int out_size, void* d_ws, size_t ws_size,
                              hipStream_t stream) {
    const float* queries = (const float*)d_in[0];
    const float* keys    = (const float*)d_in[1];
    const float* values  = (const float*)d_in[2];
    // d_in[3] = relative_encoding_lookup: DEAD CODE (overwritten in reference).
    const float* edge    = (const float*)d_in[4];
    const float* Wq = (const float*)d_in[5];
    const float* bq = (const float*)d_in[6];
    const float* Wk = (const float*)d_in[7];
    const float* bk = (const float*)d_in[8];
    const float* Wv = (const float*)d_in[9];
    const float* bv = (const float*)d_in[10];

    float* out = (float*)d_out;

    const int B = in_sizes[0] / (SEQ_L * DIM);           // 2
    const size_t scores_sz = (size_t)B * SEQ_L * SEQ_L;
    const size_t qkv_sz    = (size_t)B * SEQ_L * DIM;

    float* v_out = out + scores_sz;           // output slot 1: v
    float* q_out = out + scores_sz + qkv_sz;  // output slot 2: q
    float* k_ws  = (float*)d_ws;              // k -> scratch

    const int rows = B * SEQ_L;               // 1024

    dim3 pgrid(rows / 4, 3);
    proj_norm3_kernel<<<pgrid, 256, 0, stream>>>(
        queries, Wq, bq, q_out,
        keys,    Wk, bk, k_ws,
        values,  Wv, bv, v_out);

    qk4_kernel<<<rows / 4, 256, 0, stream>>>(q_out, k_ws, out);

    dim3 egrid(rows, 4);
    edge_kernel<<<egrid, 256, 0, stream>>>(q_out, edge, out);
}